// Round 6
// baseline (166.193 us; speedup 1.0000x reference)
//
#include <hip/hip_runtime.h>
#include <hip/hip_bf16.h>

// VectorQuantizer on MI355X — Round 6: coalesced epilogue via LDS bounce.
// z: [32, 64, 64, 64] fp32 (B,C,H,W), emb: [1024, 64] fp32.
// out: z_q [32,64,64,64] fp32 (8388608) then loss (1 float).
//
// R5 post-mortem: A-frag pre-bake worked (vq left top-5), but the R5
// epilogue stores were uncoalesced (64 lines per store instr: 16 p x 4 c).
// R6: gather 4-lanes-per-row (16 lines/load, keeps R5 load win) -> qlds
// [p][c] stride 65 (<=2-way bank aliasing = free) -> float4 stores with
// consecutive-p lanes (1KB contiguous per wave-store). LDS phases unioned
// (66 KB arena) so 2 blocks/CU co-reside; launch_bounds(1024,8) caps VGPR
// at 64 (currently 48) to guarantee it.
// Argmin: packed-key (score bits & ~1023 | inverted id) v_max_u32 tree.
// Loss from scores: ||z-e||^2 = ||z||^2 - 2(score-1), no z re-read.

#define NELEM 8388608
#define NBLK  512

typedef short sv8 __attribute__((ext_vector_type(8)));
typedef float fv4 __attribute__((ext_vector_type(4)));
typedef int   iv4 __attribute__((ext_vector_type(4)));
typedef unsigned int uint32;

__device__ __forceinline__ uint32 pack2bf(float a, float b) {
    __hip_bfloat162 h = __float22bfloat162_rn(make_float2(a, b));
    union { __hip_bfloat162 h2; uint32 u; } cvt;
    cvt.h2 = h;
    return cvt.u;             // low 16 = a, high 16 = b
}

__device__ __forceinline__ uint32 umax(uint32 a, uint32 b) { return a > b ? a : b; }

// ---- prep: codebook -> bf16 A-frags (fragment order) + e2n = 1-0.5||e||^2.
__global__ __launch_bounds__(256) void prep_kernel(
        const float* __restrict__ embf,
        iv4* __restrict__ fragws,            // 8192 units of 16B
        float* __restrict__ e2n) {           // 1024 floats
    const int t = blockIdx.x * 256 + threadIdx.x;   // 0..4095
    const int g = t >> 6, l = t & 63;
    const int code = g * 16 + (l & 15);
    const int q    = l >> 4;
    float s2 = 0.0f;
#pragma unroll
    for (int kc = 0; kc < 2; ++kc) {
        fv4 u0 = ((const fv4*)embf)[code * 16 + kc * 8 + q * 2 + 0];
        fv4 u1 = ((const fv4*)embf)[code * 16 + kc * 8 + q * 2 + 1];
        s2 += u0[0]*u0[0] + u0[1]*u0[1] + u0[2]*u0[2] + u0[3]*u0[3]
            + u1[0]*u1[0] + u1[1]*u1[1] + u1[2]*u1[2] + u1[3]*u1[3];
        iv4 pv = { (int)pack2bf(u0[0], u0[1]), (int)pack2bf(u0[2], u0[3]),
                   (int)pack2bf(u1[0], u1[1]), (int)pack2bf(u1[2], u1[3]) };
        fragws[(g * 2 + kc) * 64 + l] = pv;
    }
    s2 += __shfl_xor(s2, 16);
    s2 += __shfl_xor(s2, 32);                // full ||e_code||^2
    if (q == 0) e2n[code] = 1.0f - 0.5f * s2;
}

// LDS arena (bytes):
//  phase A: zfrag 0..32768 | kbuf 32768..50176 (256*17 u32) | zn2 50176..52224
//  phase B: qlds 0..66560 (256*65 f32)  [overlaps A after it is dead]
//  persistent: idxf 66560..67584 | lred 67584..67600
#define SMEM_BYTES 67600

__global__ __launch_bounds__(1024, 8) void vq_kernel(
        const float* __restrict__ z,
        const float* __restrict__ embf,
        const iv4* __restrict__ fragws,
        const float* __restrict__ e2n,
        float* __restrict__ out,
        float* __restrict__ blksum) {
    __shared__ char smem[SMEM_BYTES];
    iv4*    zfrag = (iv4*)smem;                       // [pt*2+kc][fraglane]
    uint32* kbuf  = (uint32*)(smem + 32768);          // [pixel][wave] stride 17
    float*  zn2   = (float*)(smem + 50176);           // [pt][s][half]
    float*  qlds  = (float*)smem;                     // [p][c] stride 65
    int*    idxf  = (int*)(smem + 66560);
    float*  lred  = (float*)(smem + 67584);

    const int tid   = threadIdx.x;
    const int blk   = blockIdx.x;
    const int batch = blk >> 4;
    const int hw0   = (blk & 15) << 8;     // 256 pixels in the 64x64 plane
    const int zb    = batch * 262144;      // + c*4096 + (hw0 + p)

    const int wv   = tid >> 6;
    const int lane = tid & 63;
    const int q    = lane >> 4;
    const int mcol = lane & 15;

    // ---- stage z -> bf16 B-frags + fp32 ||z||^2 partials
#pragma unroll
    for (int m = 0; m < 2; ++m) {
        const int R   = m * 16 + wv;       // pt*2 + kc
        const int col = hw0 + (R >> 1) * 16 + mcol;
        const int cb  = (R & 1) * 32 + q * 8;
        uint32 pk[4];
        float  sq = 0.0f;
#pragma unroll
        for (int jj = 0; jj < 4; ++jj) {
            float f0 = z[zb + (cb + jj * 2 + 0) * 4096 + col];
            float f1 = z[zb + (cb + jj * 2 + 1) * 4096 + col];
            sq += f0 * f0 + f1 * f1;
            pk[jj] = pack2bf(f0, f1);
        }
        iv4 v = { (int)pk[0], (int)pk[1], (int)pk[2], (int)pk[3] };
        zfrag[R * 64 + lane] = v;          // lane-contiguous: conflict-free
        sq += __shfl_xor(sq, 16);
        sq += __shfl_xor(sq, 32);
        if (q == 0) zn2[((R >> 1) * 16 + mcol) * 2 + (R & 1)] = sq;
    }

    // ---- A-frags: contiguous 1KB wave-loads; einit: 64B broadcast per kt
    sv8    afr[4][2];
    fv4    einit[4];
    uint32 inv[4][4];
#pragma unroll
    for (int kt = 0; kt < 4; ++kt) {
        const int g = wv * 4 + kt;
#pragma unroll
        for (int kc = 0; kc < 2; ++kc) {
            iv4 pv = fragws[(g * 2 + kc) * 64 + lane];
            afr[kt][kc] = *(sv8*)&pv;
        }
        einit[kt] = *(const fv4*)(e2n + g * 16 + q * 4);
#pragma unroll
        for (int r = 0; r < 4; ++r)
            inv[kt][r] = (uint32)(1023 - (g * 16 + q * 4 + r));
    }
    __syncthreads();

    // ---- main loop: 16 pixel-tiles, branchless key-max
#pragma unroll 4
    for (int pt = 0; pt < 16; ++pt) {
        sv8 b0 = ((const sv8*)zfrag)[(pt * 2 + 0) * 64 + lane];
        sv8 b1 = ((const sv8*)zfrag)[(pt * 2 + 1) * 64 + lane];
        uint32 kk[4];
#pragma unroll
        for (int kt = 0; kt < 4; ++kt) {
            fv4 acc = einit[kt];
            acc = __builtin_amdgcn_mfma_f32_16x16x32_bf16(afr[kt][0], b0, acc, 0, 0, 0);
            acc = __builtin_amdgcn_mfma_f32_16x16x32_bf16(afr[kt][1], b1, acc, 0, 0, 0);
            uint32 k0 = (__float_as_uint(acc[0]) & 0xFFFFFC00u) | inv[kt][0];
            uint32 k1 = (__float_as_uint(acc[1]) & 0xFFFFFC00u) | inv[kt][1];
            uint32 k2 = (__float_as_uint(acc[2]) & 0xFFFFFC00u) | inv[kt][2];
            uint32 k3 = (__float_as_uint(acc[3]) & 0xFFFFFC00u) | inv[kt][3];
            kk[kt] = umax(umax(k0, k1), umax(k2, k3));
        }
        uint32 key = umax(umax(kk[0], kk[1]), umax(kk[2], kk[3]));
        key = umax(key, (uint32)__shfl_xor((int)key, 16));
        key = umax(key, (uint32)__shfl_xor((int)key, 32));
        if (q == 0) kbuf[(pt * 16 + mcol) * 17 + wv] = key;
    }
    __syncthreads();

    // ---- per-pixel cross-wave max + loss (reads kbuf/zn2, writes idxf/lred)
    if (tid < 256) {
        uint32 best = kbuf[tid * 17];
#pragma unroll
        for (int w = 1; w < 16; ++w) best = umax(best, kbuf[tid * 17 + w]);
        const int   id = 1023 - (int)(best & 1023u);
        const float sc = __uint_as_float(best & 0xFFFFFC00u);
        idxf[tid] = id;
        float myloss = zn2[tid * 2] + zn2[tid * 2 + 1] - 2.0f * (sc - 1.0f);
#pragma unroll
        for (int off = 32; off; off >>= 1) myloss += __shfl_down(myloss, off);
        if (lane == 0) lred[wv] = myloss;
    }
    __syncthreads();

    // ---- gather code rows 4-lanes-per-row (16 lines/load) into qlds
    {
        const int p    = tid >> 2;         // pixel in block
        const int part = tid & 3;          // 16-channel slice
        const int id   = idxf[p];
#pragma unroll
        for (int j = 0; j < 4; ++j) {
            fv4 e = ((const fv4*)embf)[id * 16 + part * 4 + j];
#pragma unroll
            for (int ee = 0; ee < 4; ++ee)
                qlds[p * 65 + part * 16 + j * 4 + ee] = e[ee];
        }
    }
    __syncthreads();

    // ---- coalesced float4 stores: consecutive lanes -> consecutive p
#pragma unroll
    for (int it = 0; it < 4; ++it) {
        const int base = it * 4096 + tid * 4;     // element in [c][p] space
        const int c = base >> 8;
        const int p = base & 255;
        fv4 v;
#pragma unroll
        for (int i = 0; i < 4; ++i) v[i] = qlds[(p + i) * 65 + c];
        *(fv4*)(out + zb + c * 4096 + hw0 + p) = v;   // z + (z_q - z) == z_q
    }
    if (tid == 0) blksum[blk] = lred[0] + lred[1] + lred[2] + lred[3];
}

__global__ void fin_kernel(const float* __restrict__ blksum,
                           float* __restrict__ out_loss) {
    __shared__ float w[8];
    const int t = threadIdx.x;
    float s = blksum[t];
#pragma unroll
    for (int off = 32; off; off >>= 1) s += __shfl_down(s, off);
    if ((t & 63) == 0) w[t >> 6] = s;
    __syncthreads();
    if (t == 0) {
        float tot = 0.0f;
#pragma unroll
        for (int i = 0; i < 8; ++i) tot += w[i];
        out_loss[0] = 1.5f * tot / (float)NELEM;
    }
}

extern "C" void kernel_launch(void* const* d_in, const int* in_sizes, int n_in,
                              void* d_out, int out_size, void* d_ws, size_t ws_size,
                              hipStream_t stream) {
    const float* z    = (const float*)d_in[0];
    const float* embf = (const float*)d_in[1];
    float* out        = (float*)d_out;

    iv4*   fragws = (iv4*)d_ws;                            // 128 KB
    float* e2n    = (float*)((char*)d_ws + 131072);        // 4 KB
    float* blksum = (float*)((char*)d_ws + 131072 + 4096); // 2 KB

    prep_kernel<<<dim3(16), dim3(256), 0, stream>>>(embf, fragws, e2n);
    vq_kernel<<<dim3(NBLK), dim3(1024), 0, stream>>>(z, embf, fragws, e2n, out, blksum);
    fin_kernel<<<dim3(1), dim3(512), 0, stream>>>(blksum, out + NELEM);
}

// Round 7
// 110.153 us; speedup vs baseline: 1.5087x; 1.5087x over previous
//
#include <hip/hip_runtime.h>
#include <hip/hip_bf16.h>

// VectorQuantizer on MI355X — Round 7: spill fix + per-wave epilogue.
// z: [32, 64, 64, 64] fp32 (B,C,H,W), emb: [1024, 64] fp32.
// out: z_q [32,64,64,64] fp32 (8388608) then loss (1 float).
//
// R6 post-mortem: launch_bounds(1024,8) forced VGPR=32 -> scratch spills
// (FETCH 198MB, WRITE 82MB = spill traffic). Also bounce-buffer store
// reads were 8-way bank-conflicted. R7: launch_bounds(1024,4) (R5 was 48
// VGPR, no spill); epilogue restructured per-wave, ZERO extra barriers:
// wave wv owns pixels [wv*16,wv*16+16) — kbuf stride 20 (16B aligned) ->
// one conflict-free ds_read_b128 per lane covers 4 wave-entries, 4 lanes
// per pixel + 2 shfl_xor finish the argmax; gather 4 lanes/row (16
// lines/load); direct stores (16p x 4c per instr = 4x64B segments =
// coalesced-equivalent density). Argmin: packed key (score bits & ~1023
// | 1023-id) via v_max_u32. Loss from scores: ||z||^2 - 2(score-1).

#define NELEM 8388608
#define NBLK  512

typedef short sv8 __attribute__((ext_vector_type(8)));
typedef float fv4 __attribute__((ext_vector_type(4)));
typedef int   iv4 __attribute__((ext_vector_type(4)));
typedef unsigned int uint32;
typedef uint32 uv4 __attribute__((ext_vector_type(4)));

__device__ __forceinline__ uint32 pack2bf(float a, float b) {
    __hip_bfloat162 h = __float22bfloat162_rn(make_float2(a, b));
    union { __hip_bfloat162 h2; uint32 u; } cvt;
    cvt.h2 = h;
    return cvt.u;             // low 16 = a, high 16 = b
}

__device__ __forceinline__ uint32 umax(uint32 a, uint32 b) { return a > b ? a : b; }

// ---- prep: codebook -> bf16 A-frags (fragment order) + e2n = 1-0.5||e||^2.
__global__ __launch_bounds__(256) void prep_kernel(
        const float* __restrict__ embf,
        iv4* __restrict__ fragws,            // 8192 units of 16B
        float* __restrict__ e2n) {           // 1024 floats
    const int t = blockIdx.x * 256 + threadIdx.x;   // 0..4095
    const int g = t >> 6, l = t & 63;
    const int code = g * 16 + (l & 15);
    const int q    = l >> 4;
    float s2 = 0.0f;
#pragma unroll
    for (int kc = 0; kc < 2; ++kc) {
        fv4 u0 = ((const fv4*)embf)[code * 16 + kc * 8 + q * 2 + 0];
        fv4 u1 = ((const fv4*)embf)[code * 16 + kc * 8 + q * 2 + 1];
        s2 += u0[0]*u0[0] + u0[1]*u0[1] + u0[2]*u0[2] + u0[3]*u0[3]
            + u1[0]*u1[0] + u1[1]*u1[1] + u1[2]*u1[2] + u1[3]*u1[3];
        iv4 pv = { (int)pack2bf(u0[0], u0[1]), (int)pack2bf(u0[2], u0[3]),
                   (int)pack2bf(u1[0], u1[1]), (int)pack2bf(u1[2], u1[3]) };
        fragws[(g * 2 + kc) * 64 + l] = pv;
    }
    s2 += __shfl_xor(s2, 16);
    s2 += __shfl_xor(s2, 32);                // full ||e_code||^2
    if (q == 0) e2n[code] = 1.0f - 0.5f * s2;
}

__global__ __launch_bounds__(1024, 4) void vq_kernel(
        const float* __restrict__ z,
        const float* __restrict__ embf,
        const iv4* __restrict__ fragws,
        const float* __restrict__ e2n,
        float* __restrict__ out,
        float* __restrict__ blksum) {
    __shared__ iv4    zfrag[32 * 64];        // 32 KB  B-frags [pt*2+kc][lane]
    __shared__ uint32 kbuf[256 * 20];        // 20 KB  keys [pixel][wave], str 20
    __shared__ float  zn2[256 * 2];          //  2 KB  ||z||^2 halves per pixel
    __shared__ float  lred[16];

    const int tid   = threadIdx.x;
    const int blk   = blockIdx.x;
    const int batch = blk >> 4;
    const int hw0   = (blk & 15) << 8;       // 256 pixels in the 64x64 plane
    const int zb    = batch * 262144;        // + c*4096 + (hw0 + p)

    const int wv   = tid >> 6;
    const int lane = tid & 63;
    const int q    = lane >> 4;
    const int mcol = lane & 15;

    // ---- stage z -> bf16 B-frags + fp32 ||z||^2 partials
#pragma unroll
    for (int m = 0; m < 2; ++m) {
        const int R   = m * 16 + wv;         // pt*2 + kc
        const int col = hw0 + (R >> 1) * 16 + mcol;
        const int cb  = (R & 1) * 32 + q * 8;
        uint32 pk[4];
        float  sq = 0.0f;
#pragma unroll
        for (int jj = 0; jj < 4; ++jj) {
            float f0 = z[zb + (cb + jj * 2 + 0) * 4096 + col];
            float f1 = z[zb + (cb + jj * 2 + 1) * 4096 + col];
            sq += f0 * f0 + f1 * f1;
            pk[jj] = pack2bf(f0, f1);
        }
        iv4 v = { (int)pk[0], (int)pk[1], (int)pk[2], (int)pk[3] };
        zfrag[R * 64 + lane] = v;            // lane-contiguous: conflict-free
        sq += __shfl_xor(sq, 16);
        sq += __shfl_xor(sq, 32);
        if (q == 0) zn2[((R >> 1) * 16 + mcol) * 2 + (R & 1)] = sq;
    }

    // ---- A-frags: contiguous 1KB wave-loads; einit: 64B broadcast per kt
    sv8    afr[4][2];
    fv4    einit[4];
    uint32 inv[4][4];
#pragma unroll
    for (int kt = 0; kt < 4; ++kt) {
        const int g = wv * 4 + kt;
#pragma unroll
        for (int kc = 0; kc < 2; ++kc) {
            iv4 pv = fragws[(g * 2 + kc) * 64 + lane];
            afr[kt][kc] = *(sv8*)&pv;
        }
        einit[kt] = *(const fv4*)(e2n + g * 16 + q * 4);
#pragma unroll
        for (int r = 0; r < 4; ++r)
            inv[kt][r] = (uint32)(1023 - (g * 16 + q * 4 + r));
    }
    __syncthreads();

    // ---- main loop: 16 pixel-tiles, branchless key-max
#pragma unroll 2
    for (int pt = 0; pt < 16; ++pt) {
        sv8 b0 = ((const sv8*)zfrag)[(pt * 2 + 0) * 64 + lane];
        sv8 b1 = ((const sv8*)zfrag)[(pt * 2 + 1) * 64 + lane];
        uint32 kk[4];
#pragma unroll
        for (int kt = 0; kt < 4; ++kt) {
            fv4 acc = einit[kt];
            acc = __builtin_amdgcn_mfma_f32_16x16x32_bf16(afr[kt][0], b0, acc, 0, 0, 0);
            acc = __builtin_amdgcn_mfma_f32_16x16x32_bf16(afr[kt][1], b1, acc, 0, 0, 0);
            uint32 k0 = (__float_as_uint(acc[0]) & 0xFFFFFC00u) | inv[kt][0];
            uint32 k1 = (__float_as_uint(acc[1]) & 0xFFFFFC00u) | inv[kt][1];
            uint32 k2 = (__float_as_uint(acc[2]) & 0xFFFFFC00u) | inv[kt][2];
            uint32 k3 = (__float_as_uint(acc[3]) & 0xFFFFFC00u) | inv[kt][3];
            kk[kt] = umax(umax(k0, k1), umax(k2, k3));
        }
        uint32 key = umax(umax(kk[0], kk[1]), umax(kk[2], kk[3]));
        key = umax(key, (uint32)__shfl_xor((int)key, 16));
        key = umax(key, (uint32)__shfl_xor((int)key, 32));
        if (q == 0) kbuf[(pt * 16 + mcol) * 20 + wv] = key;   // 2-way, free
    }
    __syncthreads();

    // ---- per-wave epilogue: wave wv owns pixels [wv*16, wv*16+16).
    // 4 lanes per pixel: lane = 4*dp + e; one b128 read covers entries
    // [e*4, e*4+4) of kbuf row (stride 20 -> aligned, conflict-free).
    {
        const int dp = lane >> 2;            // 0..15  pixel within wave
        const int e  = lane & 3;             // entry quad
        const int p  = wv * 16 + dp;         // pixel in block

        uv4 kq = *(const uv4*)(kbuf + p * 20 + e * 4);
        uint32 best = umax(umax(kq[0], kq[1]), umax(kq[2], kq[3]));
        best = umax(best, (uint32)__shfl_xor((int)best, 1));
        best = umax(best, (uint32)__shfl_xor((int)best, 2));
        const int id = 1023 - (int)(best & 1023u);

        // loss (lane e==0 of each pixel group), then wave-sum over e==0 lanes
        float myloss = 0.0f;
        if (e == 0) {
            const float sc = __uint_as_float(best & 0xFFFFFC00u);
            myloss = zn2[p * 2] + zn2[p * 2 + 1] - 2.0f * (sc - 1.0f);
        }
#pragma unroll
        for (int off = 4; off < 64; off <<= 1) myloss += __shfl_down(myloss, off);
        if (lane == 0) lred[wv] = myloss;

        // gather: 4 lanes per code row (16 lines/load), 64B per lane
        // stores: fixed (jj,ee): 16 consecutive p x 4 c = 4x64B segments
#pragma unroll
        for (int jj = 0; jj < 4; ++jj) {
            fv4 ev = ((const fv4*)embf)[id * 16 + e * 4 + jj];
#pragma unroll
            for (int ee = 0; ee < 4; ++ee) {
                const int c = e * 16 + jj * 4 + ee;
                out[zb + c * 4096 + hw0 + p] = ev[ee];  // z + (z_q - z) == z_q
            }
        }
    }
    __syncthreads();
    if (tid == 0) {
        float s = 0.0f;
#pragma unroll
        for (int i = 0; i < 16; ++i) s += lred[i];
        blksum[blk] = s;
    }
}

__global__ void fin_kernel(const float* __restrict__ blksum,
                           float* __restrict__ out_loss) {
    __shared__ float w[8];
    const int t = threadIdx.x;
    float s = blksum[t];
#pragma unroll
    for (int off = 32; off; off >>= 1) s += __shfl_down(s, off);
    if ((t & 63) == 0) w[t >> 6] = s;
    __syncthreads();
    if (t == 0) {
        float tot = 0.0f;
#pragma unroll
        for (int i = 0; i < 8; ++i) tot += w[i];
        out_loss[0] = 1.5f * tot / (float)NELEM;
    }
}

extern "C" void kernel_launch(void* const* d_in, const int* in_sizes, int n_in,
                              void* d_out, int out_size, void* d_ws, size_t ws_size,
                              hipStream_t stream) {
    const float* z    = (const float*)d_in[0];
    const float* embf = (const float*)d_in[1];
    float* out        = (float*)d_out;

    iv4*   fragws = (iv4*)d_ws;                            // 128 KB
    float* e2n    = (float*)((char*)d_ws + 131072);        // 4 KB
    float* blksum = (float*)((char*)d_ws + 131072 + 4096); // 2 KB

    prep_kernel<<<dim3(16), dim3(256), 0, stream>>>(embf, fragws, e2n);
    vq_kernel<<<dim3(NBLK), dim3(1024), 0, stream>>>(z, embf, fragws, e2n, out, blksum);
    fin_kernel<<<dim3(1), dim3(512), 0, stream>>>(blksum, out + NELEM);
}